// Round 9
// baseline (1742.474 us; speedup 1.0000x reference)
//
#include <hip/hip_runtime.h>
#include <hip/hip_bf16.h>
#include <math.h>

#define N_NODES 50000
#define M_PAD   50048                    // 782 * 64
#define TILE_M  64
#define NBLK_GEMM (M_PAD / TILE_M)       // 782
#define NBLK_GAT (N_NODES / 4)           // 12500
#define N_EDGES 800000
#define EQ      (N_EDGES / 4)            // 200000 (4 edges/thread in build)
#define NBLK_BUILD ((EQ + 255) / 256)    // 782
#define F_IN 128
#define HID 64
#define HEADS 4
#define FEAT 256        // HEADS*HID
#define OUT_DIM 128
#define N_CLS 2
#define NG 500
#define SLOPE 0.2f
#define BN_EPS 1e-5f
#define ECAP 64          // ELL slots per node (incl. self at slot 0)

// prep task ranges (threads): W1T + h1bf pad + deg/ell init
#define T_W1  (F_IN * 256)               // 32768
#define T_W2  (FEAT * 256)               // 65536 -> blocks inside gemm1_build
#define NBLK_W2T (T_W2 / 256)            // 256
#define HPAD_ULL ((M_PAD - N_NODES) * FEAT / 4)   // 3072
#define PREP_THREADS (T_W1 + HPAD_ULL + N_NODES)
#define NBLK_PREP ((PREP_THREADS + 255) / 256)    // 336

typedef __attribute__((ext_vector_type(8))) short short8;
typedef __attribute__((ext_vector_type(4))) float floatx4;
typedef __attribute__((ext_vector_type(2))) float floatx2;

__device__ inline unsigned short f2bf(float f) {
    unsigned int u = __float_as_uint(f);
    unsigned int lsb = (u >> 16) & 1u;
    return (unsigned short)((u + 0x7fffu + lsb) >> 16);
}

// ===== prep: W1 transpose, h1bf pad zero, deg/ell self-init =====
__global__ __launch_bounds__(256) void prep_small(
    const float* __restrict__ W1, unsigned short* __restrict__ W1T,
    unsigned short* __restrict__ h1bf,
    int* __restrict__ deg, int* __restrict__ ell, int* __restrict__ ovf_cnt) {
    int gid = blockIdx.x * 256 + threadIdx.x;
    if (gid < T_W1) {
        int k = gid >> 8, n = gid & 255;
        W1T[n * F_IN + k] = f2bf(W1[gid]);
        return;
    }
    int j = gid - T_W1;
    if (j < HPAD_ULL) {
        ((unsigned long long*)(h1bf + (size_t)N_NODES * FEAT))[j] = 0ULL;
        return;
    }
    j -= HPAD_ULL;
    if (j < N_NODES) {
        deg[j] = 1;                       // self-loop preassigned
        ell[(size_t)j * ECAP] = j;        // slot 0 = self
        if (j == 0) *ovf_cnt = 0;
    }
}

// ==== LDS-staged GEMM core (R5-proven), templated on tile height TM ====
// LDS staging is for COALESCING, not reuse (R6 lesson).
template<int K, bool AF32, int TM>
__device__ __forceinline__ void gemm_core(
    const void* __restrict__ Av, const unsigned short* __restrict__ BT,
    const float* __restrict__ att_src, const float* __restrict__ att_dst,
    unsigned char* __restrict__ h8, float* __restrict__ a_s,
    float* __restrict__ a_d, int bid, unsigned char* smem_raw) {
    constexpr int LS = 40;      // staging row stride (bf16)
    constexpr int C8 = 272;     // fp8 C-repack row stride (bytes, 16B-aligned)
    constexpr int MI = TM / 16; // acc rows per wave
    int t = threadIdx.x;
    unsigned short* As = (unsigned short*)smem_raw;
    unsigned short* Bs = As + TM * LS;
    unsigned char*  s8 = smem_raw;
    int lane = t & 63, w = t >> 6;
    int row0 = bid * TM;
    int mrow = lane & 15, quad = lane >> 4;

    floatx4 acc[MI][4] = {};

    int rA = t >> 2, cA = (t & 3) * 8;   // rA 0..63, cA in {0,8,16,24}

    const unsigned short* Ab = (const unsigned short*)Av;
    const float* Af = (const float*)Av;

    for (int k0 = 0; k0 < K; k0 += 32) {
        #pragma unroll
        for (int j = 0; j < TM / 64; j++) {
            int r = rA + j * 64;
            if (AF32) {
                uint4 pk = make_uint4(0, 0, 0, 0);
                if (row0 + r < N_NODES) {
                    float4 f0 = *(const float4*)&Af[(long long)(row0 + r) * K + k0 + cA];
                    float4 f1 = *(const float4*)&Af[(long long)(row0 + r) * K + k0 + cA + 4];
                    pk.x = (unsigned)f2bf(f0.x) | ((unsigned)f2bf(f0.y) << 16);
                    pk.y = (unsigned)f2bf(f0.z) | ((unsigned)f2bf(f0.w) << 16);
                    pk.z = (unsigned)f2bf(f1.x) | ((unsigned)f2bf(f1.y) << 16);
                    pk.w = (unsigned)f2bf(f1.z) | ((unsigned)f2bf(f1.w) << 16);
                }
                *(uint4*)&As[r * LS + cA] = pk;
            } else {
                *(uint4*)&As[r * LS + cA] =
                    *(const uint4*)&Ab[(long long)(row0 + r) * K + k0 + cA];
            }
        }
        #pragma unroll
        for (int j = 0; j < 4; j++) {
            int r = rA + j * 64;
            *(uint4*)&Bs[r * LS + cA] = *(const uint4*)&BT[(long long)r * K + k0 + cA];
        }
        __syncthreads();
        short8 bf[4];
        #pragma unroll
        for (int ni = 0; ni < 4; ni++)
            bf[ni] = *(const short8*)&Bs[(w * 64 + ni * 16 + mrow) * LS + quad * 8];
        #pragma unroll
        for (int mi = 0; mi < MI; mi++) {
            short8 af = *(const short8*)&As[(mi * 16 + mrow) * LS + quad * 8];
            #pragma unroll
            for (int ni = 0; ni < 4; ni++)
                acc[mi][ni] = __builtin_amdgcn_mfma_f32_16x16x32_bf16(af, bf[ni],
                                                                      acc[mi][ni], 0, 0, 0);
        }
        __syncthreads();
    }

    // ---- attention scores (wave w == head w) ----
    float ats[4], atd[4];
    #pragma unroll
    for (int ni = 0; ni < 4; ni++) {
        ats[ni] = att_src[w * 64 + ni * 16 + mrow];
        atd[ni] = att_dst[w * 64 + ni * 16 + mrow];
    }
    #pragma unroll
    for (int mi = 0; mi < MI; mi++) {
        #pragma unroll
        for (int r = 0; r < 4; r++) {
            int row = row0 + mi * 16 + quad * 4 + r;
            float ps = 0.f, pd = 0.f;
            #pragma unroll
            for (int ni = 0; ni < 4; ni++) {
                float v = acc[mi][ni][r];
                ps += v * ats[ni];
                pd += v * atd[ni];
            }
            #pragma unroll
            for (int off = 1; off < 16; off <<= 1) {
                ps += __shfl_xor(ps, off);
                pd += __shfl_xor(pd, off);
            }
            if (mrow == 0 && row < N_NODES) {
                a_s[row * 4 + w] = ps;
                a_d[row * 4 + w] = pd;
            }
        }
    }

    // ---- repack C tile as fp8 through LDS, coalesced uint4 stores ----
    #pragma unroll
    for (int mi = 0; mi < MI; mi++)
        #pragma unroll
        for (int r = 0; r < 4; r++) {
            int row = mi * 16 + quad * 4 + r;
            #pragma unroll
            for (int ni = 0; ni < 4; ni += 2) {
                int pk = __builtin_amdgcn_cvt_pk_fp8_f32(acc[mi][ni][r],
                                                         acc[mi][ni + 1][r], 0, false);
                s8[row * C8 + w * 64 + ni * 16 + mrow]       = (unsigned char)(pk & 0xff);
                s8[row * C8 + w * 64 + (ni + 1) * 16 + mrow] = (unsigned char)((pk >> 8) & 0xff);
            }
        }
    __syncthreads();
    if (TM == 64) {
        int r2 = t >> 2, q = t & 3;       // 64 rows x 64 B per thread
        const uint4* sp = (const uint4*)&s8[r2 * C8 + q * 64];
        uint4* dp = (uint4*)&h8[(long long)(row0 + r2) * FEAT + q * 64];
        #pragma unroll
        for (int k = 0; k < 4; k++)
            dp[k] = sp[k];
    } else {
        int r2 = t >> 1, half = t & 1;
        const uint4* sp = (const uint4*)&s8[r2 * C8 + half * 128];
        uint4* dp = (uint4*)&h8[(long long)(row0 + r2) * FEAT + half * 128];
        #pragma unroll
        for (int k = 0; k < 8; k++)
            dp[k] = sp[k];
    }
}

// ==== L1: GEMM blocks | W2T blocks | ELL build blocks (build last) ====
__global__ __launch_bounds__(256, 4) void gemm1_build(
    const float* __restrict__ x, const unsigned short* __restrict__ BT,
    const float* __restrict__ W2, unsigned short* __restrict__ W2T,
    const float* __restrict__ att_src, const float* __restrict__ att_dst,
    unsigned char* __restrict__ h8, float* __restrict__ a_s,
    float* __restrict__ a_d,
    const int* __restrict__ src, const int* __restrict__ dst,
    int* __restrict__ deg, int* __restrict__ ell,
    int* __restrict__ ovf_cnt, int* __restrict__ ovf) {
    __shared__ __align__(16) unsigned char smem_raw[(TILE_M + FEAT) * 40 * 2];
    int bid = blockIdx.x;
    if (bid >= NBLK_GEMM + NBLK_W2T) {
        // ---------- ELL build block: 4 real edges/thread ----------
        int i = (bid - NBLK_GEMM - NBLK_W2T) * 256 + threadIdx.x;
        if (i >= EQ) return;
        int ss[4], dd[4], pp[4];
        #pragma unroll
        for (int j = 0; j < 4; j++) {
            ss[j] = src[i + j * EQ];
            dd[j] = dst[i + j * EQ];
        }
        #pragma unroll
        for (int j = 0; j < 4; j++)
            pp[j] = atomicAdd(&deg[dd[j]], 1);
        #pragma unroll
        for (int j = 0; j < 4; j++) {
            if (pp[j] < ECAP) {
                ell[(size_t)dd[j] * ECAP + pp[j]] = ss[j];
            } else {
                int k = atomicAdd(ovf_cnt, 1);
                ovf[2 * k] = ss[j]; ovf[2 * k + 1] = dd[j];
            }
        }
        return;
    }
    if (bid >= NBLK_GEMM) {
        // ---------- W2 transpose block (read by layer-2 GEMM only) ----------
        int j = (bid - NBLK_GEMM) * 256 + threadIdx.x;
        int k = j >> 8, n = j & 255;
        W2T[n * FEAT + k] = f2bf(W2[j]);
        return;
    }
    gemm_core<F_IN, true, TILE_M>(x, BT, att_src, att_dst, h8, a_s, a_d,
                                  bid, smem_raw);
}

// ===== fused GAT core, wave-per-node; fp8 gather; smem passed in =====
// smem layout: p_lds[1024]f (4096B) | o_lds[256]i (1024B) | shv[4][64]f4
// (4096B) | shg[4]i  — total 9232B, fits any caller's smem block.
template<bool POOL>
__device__ __forceinline__ void gat_core(
    const int* __restrict__ deg_arr, const int* __restrict__ ell,
    const int* __restrict__ ovf_cnt, const int* __restrict__ ovf,
    const float* __restrict__ a_s, const float* __restrict__ a_d,
    const unsigned char* __restrict__ h8, const float* __restrict__ bias,
    const float* __restrict__ g, const float* __restrict__ be,
    const float* __restrict__ rm, const float* __restrict__ rv,
    unsigned short* __restrict__ out16,
    const int* __restrict__ batch, float* __restrict__ pooled,
    int bid, unsigned char* smem) {
    int t = threadIdx.x;
    int lane = t & 63;
    int w = t >> 6;
    int hd = lane >> 4;
    int d = bid * 4 + w;

    float*  p_lds = (float*)smem;
    int*    o_lds = (int*)(smem + 4096);
    float4* shv   = (float4*)(smem + 5120);
    int*    shg   = (int*)(smem + 9216);
    float* pw = &p_lds[w * ECAP * 4];
    int*   ow = &o_lds[w * ECAP];

    const unsigned int* __restrict__ H1 = (const unsigned int*)h8;

    int deg = deg_arr[d];
    float4 ad4 = *(const float4*)&a_d[d * 4];

    float den = 0.f;
    float4 acc = make_float4(0.f, 0.f, 0.f, 0.f);

    if (deg <= ECAP) {
        float lg[4] = {-INFINITY, -INFINITY, -INFINITY, -INFINITY};
        int s = 0;
        if (lane < deg) {
            s = ell[(size_t)d * ECAP + lane];
            float4 as4 = *(const float4*)&a_s[s * 4];
            float e0 = as4.x + ad4.x; lg[0] = e0 > 0.f ? e0 : SLOPE * e0;
            float e1 = as4.y + ad4.y; lg[1] = e1 > 0.f ? e1 : SLOPE * e1;
            float e2 = as4.z + ad4.z; lg[2] = e2 > 0.f ? e2 : SLOPE * e2;
            float e3 = as4.w + ad4.w; lg[3] = e3 > 0.f ? e3 : SLOPE * e3;
        }
        ow[lane] = s * 64;                       // pad lanes -> row 0
        float mm = fmaxf(fmaxf(lg[0], lg[1]), fmaxf(lg[2], lg[3]));
        #pragma unroll
        for (int off = 1; off < 64; off <<= 1) mm = fmaxf(mm, __shfl_xor(mm, off));
        float4 pq = make_float4(0.f, 0.f, 0.f, 0.f);  // pad lanes -> p = 0
        if (lane < deg) {
            pq.x = __expf(lg[0] - mm);
            pq.y = __expf(lg[1] - mm);
            pq.z = __expf(lg[2] - mm);
            pq.w = __expf(lg[3] - mm);
        }
        *(float4*)&pw[lane * 4] = pq;
        int deg4 = (deg + 3) & ~3;
        int cu[4];
        #pragma unroll
        for (int j = 0; j < 4; j++) cu[j] = (int)H1[ow[j] + lane];
        for (int e = 0; e < deg4; e += 4) {
            int nu[4] = {0, 0, 0, 0};
            if (e + 4 < deg4) {
                #pragma unroll
                for (int j = 0; j < 4; j++) nu[j] = (int)H1[ow[e + 4 + j] + lane];
            }
            #pragma unroll
            for (int j = 0; j < 4; j++) {
                float pj = pw[(e + j) * 4 + hd];
                den += pj;
                floatx2 lo = __builtin_amdgcn_cvt_pk_f32_fp8(cu[j], false);
                floatx2 hi = __builtin_amdgcn_cvt_pk_f32_fp8(cu[j], true);
                acc.x += pj * lo.x; acc.y += pj * lo.y;
                acc.z += pj * hi.x; acc.w += pj * hi.y;
            }
            #pragma unroll
            for (int j = 0; j < 4; j++) cu[j] = nu[j];
        }
    } else {
        // exact online path: ELL chunk (ECAP edges) + overflow scan
        float m_old;
        {
            int s = ell[(size_t)d * ECAP + lane];
            ow[lane] = s * 64;
            float4 as4 = *(const float4*)&a_s[s * 4];
            float lg[4];
            float e0 = as4.x + ad4.x; lg[0] = e0 > 0.f ? e0 : SLOPE * e0;
            float e1 = as4.y + ad4.y; lg[1] = e1 > 0.f ? e1 : SLOPE * e1;
            float e2 = as4.z + ad4.z; lg[2] = e2 > 0.f ? e2 : SLOPE * e2;
            float e3 = as4.w + ad4.w; lg[3] = e3 > 0.f ? e3 : SLOPE * e3;
            float mm = fmaxf(fmaxf(lg[0], lg[1]), fmaxf(lg[2], lg[3]));
            #pragma unroll
            for (int off = 1; off < 64; off <<= 1) mm = fmaxf(mm, __shfl_xor(mm, off));
            m_old = mm;
            float4 pq;
            pq.x = __expf(lg[0] - mm);
            pq.y = __expf(lg[1] - mm);
            pq.z = __expf(lg[2] - mm);
            pq.w = __expf(lg[3] - mm);
            *(float4*)&pw[lane * 4] = pq;
            for (int e = 0; e < ECAP; e++) {
                int oA = ow[e];
                float pA = pw[e * 4 + hd];
                int uA = (int)H1[oA + lane];
                den += pA;
                floatx2 a0 = __builtin_amdgcn_cvt_pk_f32_fp8(uA, false);
                floatx2 a1 = __builtin_amdgcn_cvt_pk_f32_fp8(uA, true);
                acc.x += pA * a0.x; acc.y += pA * a0.y;
                acc.z += pA * a1.x; acc.w += pA * a1.y;
            }
        }
        int nov = *ovf_cnt;
        for (int i = 0; i < nov; i++) {
            int s2 = ovf[2 * i], d2 = ovf[2 * i + 1];
            if (d2 != d) continue;
            float4 as4 = *(const float4*)&a_s[s2 * 4];
            float lg[4];
            float e0 = as4.x + ad4.x; lg[0] = e0 > 0.f ? e0 : SLOPE * e0;
            float e1 = as4.y + ad4.y; lg[1] = e1 > 0.f ? e1 : SLOPE * e1;
            float e2 = as4.z + ad4.z; lg[2] = e2 > 0.f ? e2 : SLOPE * e2;
            float e3 = as4.w + ad4.w; lg[3] = e3 > 0.f ? e3 : SLOPE * e3;
            float mmax = fmaxf(fmaxf(lg[0], lg[1]), fmaxf(lg[2], lg[3]));
            float m_new = fmaxf(m_old, mmax);
            float alpha = __expf(m_old - m_new);
            m_old = m_new;
            float ph = __expf(lg[hd] - m_new);
            acc.x *= alpha; acc.y *= alpha; acc.z *= alpha; acc.w *= alpha;
            den = den * alpha + ph;
            int u = (int)H1[s2 * 64 + lane];
            floatx2 a0 = __builtin_amdgcn_cvt_pk_f32_fp8(u, false);
            floatx2 a1 = __builtin_amdgcn_cvt_pk_f32_fp8(u, true);
            acc.x += ph * a0.x; acc.y += ph * a0.y;
            acc.z += ph * a1.x; acc.w += ph * a1.y;
        }
    }
    float inv = 1.f / den;
    int c0 = lane * 4;
    float4 bi = *(const float4*)&bias[c0];
    float4 gg = *(const float4*)&g[c0];
    float4 bb = *(const float4*)&be[c0];
    float4 mm4 = *(const float4*)&rm[c0];
    float4 vv = *(const float4*)&rv[c0];
    float v0 = fmaxf(acc.x * inv + bi.x, 0.f);
    float v1 = fmaxf(acc.y * inv + bi.y, 0.f);
    float v2 = fmaxf(acc.z * inv + bi.z, 0.f);
    float v3 = fmaxf(acc.w * inv + bi.w, 0.f);
    v0 = (v0 - mm4.x) * rsqrtf(vv.x + BN_EPS) * gg.x + bb.x;
    v1 = (v1 - mm4.y) * rsqrtf(vv.y + BN_EPS) * gg.y + bb.y;
    v2 = (v2 - mm4.z) * rsqrtf(vv.z + BN_EPS) * gg.z + bb.z;
    v3 = (v3 - mm4.w) * rsqrtf(vv.w + BN_EPS) * gg.w + bb.w;
    if (!POOL) {
        // regular store (consumer GEMM reads this soon -> keep in L2)
        unsigned long long o =
            (unsigned long long)f2bf(v0) |
            ((unsigned long long)f2bf(v1) << 16) |
            ((unsigned long long)f2bf(v2) << 32) |
            ((unsigned long long)f2bf(v3) << 48);
        *(unsigned long long*)&out16[(long long)d * FEAT + c0] = o;
    } else {
        shv[w * 64 + lane] = make_float4(v0, v1, v2, v3);
        if (lane == 0) shg[w] = (int)batch[d];
        __syncthreads();
        int cl = t >> 2, ce = t & 3;
        float r0 = ((const float*)&shv[0 * 64 + cl])[ce];
        float r1 = ((const float*)&shv[1 * 64 + cl])[ce];
        float r2 = ((const float*)&shv[2 * 64 + cl])[ce];
        float r3 = ((const float*)&shv[3 * 64 + cl])[ce];
        int g0 = shg[0], g1 = shg[1], g2 = shg[2], g3 = shg[3];
        if (g0 == g3) {
            atomicAdd(&pooled[g0 * FEAT + t], r0 + r1 + r2 + r3);
        } else {
            float sum = r0;
            int gp = g0;
            if (g1 == gp) sum += r1; else { atomicAdd(&pooled[gp * FEAT + t], sum); gp = g1; sum = r1; }
            if (g2 == gp) sum += r2; else { atomicAdd(&pooled[gp * FEAT + t], sum); gp = g2; sum = r2; }
            if (g3 == gp) sum += r3; else { atomicAdd(&pooled[gp * FEAT + t], sum); gp = g3; sum = r3; }
            atomicAdd(&pooled[gp * FEAT + t], sum);
        }
    }
}

// ==== merged: gat1 producer blocks (12500) + layer-2 GEMM consumers (782) ====
// Consumer tile r needs h1bf rows 64r..64r+63 = gat blocks 16r..16r+15.
// Producers release-increment cnt[bid>>4]; consumers acquire-spin. Safety:
// consumers (782) < resident slots (LDS 25.6KB -> 6 blk/CU * 256 = 1536) and
// are last in the grid, so producers always retain slots -> no deadlock.
__global__ __launch_bounds__(256, 2) void gat1_gemm2(
    const int* __restrict__ deg_arr, const int* __restrict__ ell,
    const int* __restrict__ ovf_cnt, const int* __restrict__ ovf,
    const float* __restrict__ a_s1, const float* __restrict__ a_d1,
    const unsigned char* __restrict__ h8a, const float* __restrict__ b1,
    const float* __restrict__ g1, const float* __restrict__ be1,
    const float* __restrict__ rm1, const float* __restrict__ rv1,
    unsigned short* __restrict__ h1bf,
    const unsigned short* __restrict__ W2T,
    const float* __restrict__ att_s2, const float* __restrict__ att_d2,
    unsigned char* __restrict__ h8b, float* __restrict__ a_s2,
    float* __restrict__ a_d2, int* __restrict__ cnt) {
    __shared__ __align__(16) unsigned char smem_raw[(TILE_M + FEAT) * 40 * 2];
    int bid = blockIdx.x;
    if (bid < NBLK_GAT) {
        gat_core<false>(deg_arr, ell, ovf_cnt, ovf, a_s1, a_d1, h8a,
                        b1, g1, be1, rm1, rv1, h1bf, nullptr, nullptr,
                        bid, smem_raw);
        __threadfence();          // each thread: h1bf stores device-visible
        __syncthreads();
        if (threadIdx.x == 0)
            __hip_atomic_fetch_add(&cnt[bid >> 4], 1, __ATOMIC_RELEASE,
                                   __HIP_MEMORY_SCOPE_AGENT);
        return;
    }
    int r = bid - NBLK_GAT;
    if (threadIdx.x == 0) {
        int target = NBLK_GAT - 16 * r;
        if (target > 16) target = 16;
        while (__hip_atomic_load(&cnt[r], __ATOMIC_ACQUIRE,
                                 __HIP_MEMORY_SCOPE_AGENT) < target)
            __builtin_amdgcn_s_sleep(16);
    }
    __syncthreads();
    gemm_core<FEAT, false, TILE_M>(h1bf, W2T, att_s2, att_d2, h8b,
                                   a_s2, a_d2, r, smem_raw);
}

// ==== layer-2 GAT with fused BN + graph mean-pool accumulation ====
__global__ __launch_bounds__(256) void gat2_pool(
    const int* __restrict__ deg_arr, const int* __restrict__ ell,
    const int* __restrict__ ovf_cnt, const int* __restrict__ ovf,
    const float* __restrict__ a_s, const float* __restrict__ a_d,
    const unsigned char* __restrict__ h8, const float* __restrict__ bias,
    const float* __restrict__ g, const float* __restrict__ be,
    const float* __restrict__ rm, const float* __restrict__ rv,
    const int* __restrict__ batch, float* __restrict__ pooled) {
    __shared__ __align__(16) unsigned char smem_raw[9232 + 16];
    gat_core<true>(deg_arr, ell, ovf_cnt, ovf, a_s, a_d, h8, bias, g, be,
                   rm, rv, nullptr, batch, pooled, blockIdx.x, smem_raw);
}

// ===== head: pooled/cnt -> relu(@lw1+lb1) @ lw2 + lb2 =====
__global__ __launch_bounds__(256) void head_mlp(
    const float* __restrict__ pooled, const int* __restrict__ batch,
    const float* __restrict__ lw1, const float* __restrict__ lb1,
    const float* __restrict__ lw2, const float* __restrict__ lb2,
    float* __restrict__ out) {
    int gph = blockIdx.x;
    int t = threadIdx.x;
    __shared__ float pl[FEAT];
    __shared__ float zl[OUT_DIM];
    __shared__ int lo_s, hi_s;
    if (t == 0) {
        int lo = 0, hi = N_NODES;
        while (lo < hi) { int mid = (lo + hi) >> 1; if (batch[mid] < gph) lo = mid + 1; else hi = mid; }
        lo_s = lo;
        int lo2 = 0, hi2 = N_NODES;
        while (lo2 < hi2) { int mid = (lo2 + hi2) >> 1; if (batch[mid] < gph + 1) lo2 = mid + 1; else hi2 = mid; }
        hi_s = lo2;
    }
    __syncthreads();
    float cnt = fmaxf((float)(hi_s - lo_s), 1.f);
    pl[t] = pooled[gph * FEAT + t] / cnt;
    __syncthreads();
    int j = t >> 1, kh = t & 1;
    float zp = 0.f;
    #pragma unroll 8
    for (int k = kh * 128; k < kh * 128 + 128; k++)
        zp += pl[k] * lw1[k * OUT_DIM + j];
    zp += __shfl_xor(zp, 1);
    if (kh == 0) zl[j] = fmaxf(zp + lb1[j], 0.f);
    __syncthreads();
    int w = t >> 6, lane = t & 63;
    if (w < 2) {
        float p = zl[lane] * lw2[lane * 2 + w] + zl[lane + 64] * lw2[(lane + 64) * 2 + w];
        #pragma unroll
        for (int off = 1; off < 64; off <<= 1) p += __shfl_xor(p, off);
        if (lane == 0) out[gph * 2 + w] = p + lb2[w];
    }
}

extern "C" void kernel_launch(void* const* d_in, const int* in_sizes, int n_in,
                              void* d_out, int out_size, void* d_ws, size_t ws_size,
                              hipStream_t stream) {
    const float* x       = (const float*)d_in[0];
    const int*   ei      = (const int*)d_in[1];
    const int*   batch   = (const int*)d_in[2];
    const float* W1      = (const float*)d_in[3];
    const float* att_s1  = (const float*)d_in[4];
    const float* att_d1  = (const float*)d_in[5];
    const float* b1      = (const float*)d_in[6];
    const float* g1      = (const float*)d_in[7];
    const float* be1     = (const float*)d_in[8];
    const float* rm1     = (const float*)d_in[9];
    const float* rv1     = (const float*)d_in[10];
    const float* W2      = (const float*)d_in[11];
    const float* att_s2  = (const float*)d_in[12];
    const float* att_d2  = (const float*)d_in[13];
    const float* b2      = (const float*)d_in[14];
    const float* g2      = (const float*)d_in[15];
    const float* be2     = (const float*)d_in[16];
    const float* rm2     = (const float*)d_in[17];
    const float* rv2     = (const float*)d_in[18];
    const float* lw1     = (const float*)d_in[19];
    const float* lb1     = (const float*)d_in[20];
    const float* lw2     = (const float*)d_in[21];
    const float* lb2     = (const float*)d_in[22];
    float* out           = (float*)d_out;

    const int* src = ei;
    const int* dst = ei + N_EDGES;

    char* p = (char*)d_ws;
    auto carve = [&p](size_t bytes) -> void* {
        void* r = (void*)p;
        p += (bytes + 63) & ~(size_t)63;
        return r;
    };
    float* pooled = (float*)carve(sizeof(float) * NG * FEAT);        // 512000 B
    int*   cnt    = (int*)carve(sizeof(int) * NBLK_GEMM);            // 3128 B
    float* a_s1   = (float*)carve(sizeof(float) * N_NODES * HEADS);
    float* a_d1   = (float*)carve(sizeof(float) * N_NODES * HEADS);
    float* a_s2   = (float*)carve(sizeof(float) * N_NODES * HEADS);
    float* a_d2   = (float*)carve(sizeof(float) * N_NODES * HEADS);
    int*   deg    = (int*)carve(sizeof(int) * N_NODES);
    int*   ovf_cnt= (int*)carve(sizeof(int) * 16);
    int*   ell    = (int*)carve(sizeof(int) * (size_t)N_NODES * ECAP);
    int*   ovf    = (int*)carve(sizeof(int) * 2 * (N_EDGES + N_NODES));
    unsigned char*  h8a  = (unsigned char*)carve((size_t)M_PAD * FEAT);
    unsigned char*  h8b  = (unsigned char*)carve((size_t)M_PAD * FEAT);
    unsigned short* h1bf = (unsigned short*)carve(sizeof(short) * (size_t)M_PAD * FEAT);
    unsigned short* w1t  = (unsigned short*)carve(sizeof(short) * FEAT * F_IN);
    unsigned short* w2t  = (unsigned short*)carve(sizeof(short) * FEAT * FEAT);

    // ---- zero pooled accumulator + tile counters (contiguous carves) ----
    hipMemsetAsync(pooled, 0, sizeof(float) * NG * FEAT + 3136, stream);

    // ---- prep: W1T, h1bf pad, deg/ell self-init ----
    prep_small<<<NBLK_PREP, 256, 0, stream>>>(W1, w1t, h1bf, deg, ell, ovf_cnt);

    // ---- Layer 1: GEMM | W2T | ELL build (build last), one launch ----
    gemm1_build<<<NBLK_GEMM + NBLK_W2T + NBLK_BUILD, 256, 0, stream>>>(
        x, w1t, W2, w2t, att_s1, att_d1, h8a, a_s1, a_d1,
        src, dst, deg, ell, ovf_cnt, ovf);

    // ---- gat1 producers + layer-2 GEMM consumers, overlapped ----
    gat1_gemm2<<<NBLK_GAT + NBLK_GEMM, 256, 0, stream>>>(
        deg, ell, ovf_cnt, ovf, a_s1, a_d1, h8a,
        b1, g1, be1, rm1, rv1, h1bf,
        w2t, att_s2, att_d2, h8b, a_s2, a_d2, cnt);

    // ---- layer-2 GAT + fused BN/pool ----
    gat2_pool<<<NBLK_GAT, 256, 0, stream>>>(deg, ell, ovf_cnt, ovf, a_s2, a_d2,
                                            h8b, b2, g2, be2, rm2, rv2,
                                            batch, pooled);

    // ---- head MLP ----
    head_mlp<<<NG, 256, 0, stream>>>(pooled, batch, lw1, lb1, lw2, lb2, out);
}

// Round 10
// 285.378 us; speedup vs baseline: 6.1058x; 6.1058x over previous
//
#include <hip/hip_runtime.h>
#include <hip/hip_bf16.h>
#include <math.h>

#define N_NODES 50000
#define M_PAD   50048                    // 782 * 64
#define TILE_M  64
#define NBLK_GEMM (M_PAD / TILE_M)       // 782
#define NBLK_GEMM2 (M_PAD / 128)         // 391 (128-row tiles for L2 GEMM)
#define NBLK_GAT (N_NODES / 4)           // 12500
#define N_EDGES 800000
#define E8      (N_EDGES / 8)            // 100000 (8 edges/thread in build)
#define NBLK_BUILD ((E8 + 255) / 256)    // 391
#define F_IN 128
#define HID 64
#define HEADS 4
#define FEAT 256        // HEADS*HID
#define OUT_DIM 128
#define N_CLS 2
#define NG 500
#define SLOPE 0.2f
#define BN_EPS 1e-5f
#define ECAP 64          // ELL slots per node (incl. self at slot 0)

// prep task ranges (threads): W1T | h1bf pad | deg/ell init | pooled zero
#define T_W1  (F_IN * 256)               // 32768
#define T_W2  (FEAT * 256)               // 65536 -> blocks inside gemm1_build
#define NBLK_W2T (T_W2 / 256)            // 256
#define HPAD_ULL ((M_PAD - N_NODES) * FEAT / 4)   // 3072
#define POOLZ (NG * FEAT / 4)            // 32000 float4 zeroes
#define PREP_THREADS (T_W1 + HPAD_ULL + N_NODES + POOLZ)
#define NBLK_PREP ((PREP_THREADS + 255) / 256)    // 462

typedef __attribute__((ext_vector_type(8))) short short8;
typedef __attribute__((ext_vector_type(4))) float floatx4;
typedef __attribute__((ext_vector_type(2))) float floatx2;

__device__ inline unsigned short f2bf(float f) {
    unsigned int u = __float_as_uint(f);
    unsigned int lsb = (u >> 16) & 1u;
    return (unsigned short)((u + 0x7fffu + lsb) >> 16);
}

// ===== prep: W1 transpose, h1bf pad zero, deg/ell self-init, pooled zero ====
__global__ __launch_bounds__(256) void prep_small(
    const float* __restrict__ W1, unsigned short* __restrict__ W1T,
    unsigned short* __restrict__ h1bf,
    int* __restrict__ deg, int* __restrict__ ell, int* __restrict__ ovf_cnt,
    float4* __restrict__ pooled4) {
    int gid = blockIdx.x * 256 + threadIdx.x;
    if (gid < T_W1) {
        int k = gid >> 8, n = gid & 255;
        W1T[n * F_IN + k] = f2bf(W1[gid]);
        return;
    }
    int j = gid - T_W1;
    if (j < HPAD_ULL) {
        ((unsigned long long*)(h1bf + (size_t)N_NODES * FEAT))[j] = 0ULL;
        return;
    }
    j -= HPAD_ULL;
    if (j < N_NODES) {
        deg[j] = 1;                       // self-loop preassigned
        ell[(size_t)j * ECAP] = j;        // slot 0 = self
        if (j == 0) *ovf_cnt = 0;
        return;
    }
    j -= N_NODES;
    if (j < POOLZ)
        pooled4[j] = make_float4(0.f, 0.f, 0.f, 0.f);
}

// ==== LDS-staged GEMM core (R5-proven), templated on tile height TM ====
// LDS staging is for COALESCING, not reuse (R6 lesson: dropping it cost
// +13us from 64-lane scattered fragment loads).
template<int K, bool AF32, int TM>
__device__ __forceinline__ void gemm_core(
    const void* __restrict__ Av, const unsigned short* __restrict__ BT,
    const float* __restrict__ att_src, const float* __restrict__ att_dst,
    unsigned char* __restrict__ h8, float* __restrict__ a_s,
    float* __restrict__ a_d, int bid, unsigned char* smem_raw) {
    constexpr int LS = 40;      // staging row stride (bf16)
    constexpr int C8 = 272;     // fp8 C-repack row stride (bytes, 16B-aligned)
    constexpr int MI = TM / 16; // acc rows per wave
    int t = threadIdx.x;
    unsigned short* As = (unsigned short*)smem_raw;
    unsigned short* Bs = As + TM * LS;
    unsigned char*  s8 = smem_raw;
    int lane = t & 63, w = t >> 6;
    int row0 = bid * TM;
    int mrow = lane & 15, quad = lane >> 4;

    floatx4 acc[MI][4] = {};

    int rA = t >> 2, cA = (t & 3) * 8;   // rA 0..63, cA in {0,8,16,24}

    const unsigned short* Ab = (const unsigned short*)Av;
    const float* Af = (const float*)Av;

    for (int k0 = 0; k0 < K; k0 += 32) {
        #pragma unroll
        for (int j = 0; j < TM / 64; j++) {
            int r = rA + j * 64;
            if (AF32) {
                uint4 pk = make_uint4(0, 0, 0, 0);
                if (row0 + r < N_NODES) {
                    float4 f0 = *(const float4*)&Af[(long long)(row0 + r) * K + k0 + cA];
                    float4 f1 = *(const float4*)&Af[(long long)(row0 + r) * K + k0 + cA + 4];
                    pk.x = (unsigned)f2bf(f0.x) | ((unsigned)f2bf(f0.y) << 16);
                    pk.y = (unsigned)f2bf(f0.z) | ((unsigned)f2bf(f0.w) << 16);
                    pk.z = (unsigned)f2bf(f1.x) | ((unsigned)f2bf(f1.y) << 16);
                    pk.w = (unsigned)f2bf(f1.z) | ((unsigned)f2bf(f1.w) << 16);
                }
                *(uint4*)&As[r * LS + cA] = pk;
            } else {
                *(uint4*)&As[r * LS + cA] =
                    *(const uint4*)&Ab[(long long)(row0 + r) * K + k0 + cA];
            }
        }
        #pragma unroll
        for (int j = 0; j < 4; j++) {
            int r = rA + j * 64;
            *(uint4*)&Bs[r * LS + cA] = *(const uint4*)&BT[(long long)r * K + k0 + cA];
        }
        __syncthreads();
        short8 bf[4];
        #pragma unroll
        for (int ni = 0; ni < 4; ni++)
            bf[ni] = *(const short8*)&Bs[(w * 64 + ni * 16 + mrow) * LS + quad * 8];
        #pragma unroll
        for (int mi = 0; mi < MI; mi++) {
            short8 af = *(const short8*)&As[(mi * 16 + mrow) * LS + quad * 8];
            #pragma unroll
            for (int ni = 0; ni < 4; ni++)
                acc[mi][ni] = __builtin_amdgcn_mfma_f32_16x16x32_bf16(af, bf[ni],
                                                                      acc[mi][ni], 0, 0, 0);
        }
        __syncthreads();
    }

    // ---- attention scores (wave w == head w) ----
    float ats[4], atd[4];
    #pragma unroll
    for (int ni = 0; ni < 4; ni++) {
        ats[ni] = att_src[w * 64 + ni * 16 + mrow];
        atd[ni] = att_dst[w * 64 + ni * 16 + mrow];
    }
    #pragma unroll
    for (int mi = 0; mi < MI; mi++) {
        #pragma unroll
        for (int r = 0; r < 4; r++) {
            int row = row0 + mi * 16 + quad * 4 + r;
            float ps = 0.f, pd = 0.f;
            #pragma unroll
            for (int ni = 0; ni < 4; ni++) {
                float v = acc[mi][ni][r];
                ps += v * ats[ni];
                pd += v * atd[ni];
            }
            #pragma unroll
            for (int off = 1; off < 16; off <<= 1) {
                ps += __shfl_xor(ps, off);
                pd += __shfl_xor(pd, off);
            }
            if (mrow == 0 && row < N_NODES) {
                a_s[row * 4 + w] = ps;
                a_d[row * 4 + w] = pd;
            }
        }
    }

    // ---- repack C tile as fp8 through LDS, coalesced uint4 stores ----
    #pragma unroll
    for (int mi = 0; mi < MI; mi++)
        #pragma unroll
        for (int r = 0; r < 4; r++) {
            int row = mi * 16 + quad * 4 + r;
            #pragma unroll
            for (int ni = 0; ni < 4; ni += 2) {
                int pk = __builtin_amdgcn_cvt_pk_fp8_f32(acc[mi][ni][r],
                                                         acc[mi][ni + 1][r], 0, false);
                s8[row * C8 + w * 64 + ni * 16 + mrow]       = (unsigned char)(pk & 0xff);
                s8[row * C8 + w * 64 + (ni + 1) * 16 + mrow] = (unsigned char)((pk >> 8) & 0xff);
            }
        }
    __syncthreads();
    if (TM == 64) {
        int r2 = t >> 2, q = t & 3;       // 64 rows x 64 B per thread
        const uint4* sp = (const uint4*)&s8[r2 * C8 + q * 64];
        uint4* dp = (uint4*)&h8[(long long)(row0 + r2) * FEAT + q * 64];
        #pragma unroll
        for (int k = 0; k < 4; k++)
            dp[k] = sp[k];
    } else {
        int r2 = t >> 1, half = t & 1;    // 128 rows x 128 B per thread
        const uint4* sp = (const uint4*)&s8[r2 * C8 + half * 128];
        uint4* dp = (uint4*)&h8[(long long)(row0 + r2) * FEAT + half * 128];
        #pragma unroll
        for (int k = 0; k < 8; k++)
            dp[k] = sp[k];
    }
}

// ==== L1: GEMM blocks | W2T blocks | ELL build blocks (build last) ====
// Build is 8 edges/thread: more outstanding atomics per thread, fewer waves
// contending the fabric (floor was ~54us at 4/thread).
__global__ __launch_bounds__(256, 4) void gemm1_build(
    const float* __restrict__ x, const unsigned short* __restrict__ BT,
    const float* __restrict__ W2, unsigned short* __restrict__ W2T,
    const float* __restrict__ att_src, const float* __restrict__ att_dst,
    unsigned char* __restrict__ h8, float* __restrict__ a_s,
    float* __restrict__ a_d,
    const int* __restrict__ src, const int* __restrict__ dst,
    int* __restrict__ deg, int* __restrict__ ell,
    int* __restrict__ ovf_cnt, int* __restrict__ ovf) {
    __shared__ __align__(16) unsigned char smem_raw[(TILE_M + FEAT) * 40 * 2];
    int bid = blockIdx.x;
    if (bid >= NBLK_GEMM + NBLK_W2T) {
        // ---------- ELL build block: 8 real edges/thread ----------
        int i = (bid - NBLK_GEMM - NBLK_W2T) * 256 + threadIdx.x;
        if (i >= E8) return;
        int ss[8], dd[8], pp[8];
        #pragma unroll
        for (int j = 0; j < 8; j++) {
            ss[j] = src[i + j * E8];
            dd[j] = dst[i + j * E8];
        }
        #pragma unroll
        for (int j = 0; j < 8; j++)
            pp[j] = atomicAdd(&deg[dd[j]], 1);
        #pragma unroll
        for (int j = 0; j < 8; j++) {
            if (pp[j] < ECAP) {
                ell[(size_t)dd[j] * ECAP + pp[j]] = ss[j];
            } else {
                int k = atomicAdd(ovf_cnt, 1);
                ovf[2 * k] = ss[j]; ovf[2 * k + 1] = dd[j];
            }
        }
        return;
    }
    if (bid >= NBLK_GEMM) {
        // ---------- W2 transpose block (read by gemm2k only) ----------
        int j = (bid - NBLK_GEMM) * 256 + threadIdx.x;
        int k = j >> 8, n = j & 255;
        W2T[n * FEAT + k] = f2bf(W2[j]);
        return;
    }
    gemm_core<F_IN, true, TILE_M>(x, BT, att_src, att_dst, h8, a_s, a_d,
                                  bid, smem_raw);
}

// ==== L2: pure GEMM, 128-row tiles ====
__global__ __launch_bounds__(256, 2) void gemm2k(
    const unsigned short* __restrict__ Ab, const unsigned short* __restrict__ BT,
    const float* __restrict__ att_src, const float* __restrict__ att_dst,
    unsigned char* __restrict__ h8, float* __restrict__ a_s,
    float* __restrict__ a_d) {
    __shared__ __align__(16) unsigned char smem_raw[128 * 272];  // 34816 B
    gemm_core<FEAT, false, 128>(Ab, BT, att_src, att_dst, h8, a_s, a_d,
                                blockIdx.x, smem_raw);
}

// ===== fused GAT, wave-per-node; fp8 gather from ELL, packed decode =====
// POOL=true (layer 2): BN'd outputs combined across the block's 4 nodes in
// LDS (batch-sorted -> usually one graph) and atomically accumulated into
// pooled[graph][col].
template<bool POOL>
__device__ __forceinline__ void gat_core(
    const int* __restrict__ deg_arr, const int* __restrict__ ell,
    const int* __restrict__ ovf_cnt, const int* __restrict__ ovf,
    const float* __restrict__ a_s, const float* __restrict__ a_d,
    const unsigned char* __restrict__ h8, const float* __restrict__ bias,
    const float* __restrict__ g, const float* __restrict__ be,
    const float* __restrict__ rm, const float* __restrict__ rv,
    unsigned short* __restrict__ out16,
    const int* __restrict__ batch, float* __restrict__ pooled) {
    int t = threadIdx.x;
    int lane = t & 63;
    int w = t >> 6;
    int hd = lane >> 4;
    int d = blockIdx.x * 4 + w;

    __shared__ float p_lds[4 * ECAP * 4];
    __shared__ int   o_lds[4 * ECAP];
    __shared__ float4 shv[4][64];
    __shared__ int    shg[4];
    float* pw = &p_lds[w * ECAP * 4];
    int*   ow = &o_lds[w * ECAP];

    const unsigned int* __restrict__ H1 = (const unsigned int*)h8;

    int deg = deg_arr[d];
    float4 ad4 = *(const float4*)&a_d[d * 4];

    float den = 0.f;
    float4 acc = make_float4(0.f, 0.f, 0.f, 0.f);

    if (deg <= ECAP) {
        float lg[4] = {-INFINITY, -INFINITY, -INFINITY, -INFINITY};
        int s = 0;
        if (lane < deg) {
            s = ell[(size_t)d * ECAP + lane];
            float4 as4 = *(const float4*)&a_s[s * 4];
            float e0 = as4.x + ad4.x; lg[0] = e0 > 0.f ? e0 : SLOPE * e0;
            float e1 = as4.y + ad4.y; lg[1] = e1 > 0.f ? e1 : SLOPE * e1;
            float e2 = as4.z + ad4.z; lg[2] = e2 > 0.f ? e2 : SLOPE * e2;
            float e3 = as4.w + ad4.w; lg[3] = e3 > 0.f ? e3 : SLOPE * e3;
        }
        ow[lane] = s * 64;                       // pad lanes -> row 0
        float mm = fmaxf(fmaxf(lg[0], lg[1]), fmaxf(lg[2], lg[3]));
        #pragma unroll
        for (int off = 1; off < 64; off <<= 1) mm = fmaxf(mm, __shfl_xor(mm, off));
        float4 pq = make_float4(0.f, 0.f, 0.f, 0.f);  // pad lanes -> p = 0
        if (lane < deg) {
            pq.x = __expf(lg[0] - mm);
            pq.y = __expf(lg[1] - mm);
            pq.z = __expf(lg[2] - mm);
            pq.w = __expf(lg[3] - mm);
        }
        *(float4*)&pw[lane * 4] = pq;
        int deg4 = (deg + 3) & ~3;
        int cu[4];
        #pragma unroll
        for (int j = 0; j < 4; j++) cu[j] = (int)H1[ow[j] + lane];
        for (int e = 0; e < deg4; e += 4) {
            int nu[4] = {0, 0, 0, 0};
            if (e + 4 < deg4) {
                #pragma unroll
                for (int j = 0; j < 4; j++) nu[j] = (int)H1[ow[e + 4 + j] + lane];
            }
            #pragma unroll
            for (int j = 0; j < 4; j++) {
                float pj = pw[(e + j) * 4 + hd];
                den += pj;
                floatx2 lo = __builtin_amdgcn_cvt_pk_f32_fp8(cu[j], false);
                floatx2 hi = __builtin_amdgcn_cvt_pk_f32_fp8(cu[j], true);
                acc.x += pj * lo.x; acc.y += pj * lo.y;
                acc.z += pj * hi.x; acc.w += pj * hi.y;
            }
            #pragma unroll
            for (int j = 0; j < 4; j++) cu[j] = nu[j];
        }
    } else {
        // exact online path: ELL chunk (ECAP edges) + overflow scan
        float m_old;
        {
            int s = ell[(size_t)d * ECAP + lane];
            ow[lane] = s * 64;
            float4 as4 = *(const float4*)&a_s[s * 4];
            float lg[4];
            float e0 = as4.x + ad4.x; lg[0] = e0 > 0.f ? e0 : SLOPE * e0;
            float e1 = as4.y + ad4.y; lg[1] = e1 > 0.f ? e1 : SLOPE * e1;
            float e2 = as4.z + ad4.z; lg[2] = e2 > 0.f ? e2 : SLOPE * e2;
            float e3 = as4.w + ad4.w; lg[3] = e3 > 0.f ? e3 : SLOPE * e3;
            float mm = fmaxf(fmaxf(lg[0], lg[1]), fmaxf(lg[2], lg[3]));
            #pragma unroll
            for (int off = 1; off < 64; off <<= 1) mm = fmaxf(mm, __shfl_xor(mm, off));
            m_old = mm;
            float4 pq;
            pq.x = __expf(lg[0] - mm);
            pq.y = __expf(lg[1] - mm);
            pq.z = __expf(lg[2] - mm);
            pq.w = __expf(lg[3] - mm);
            *(float4*)&pw[lane * 4] = pq;
            for (int e = 0; e < ECAP; e++) {
                int oA = ow[e];
                float pA = pw[e * 4 + hd];
                int uA = (int)H1[oA + lane];
                den += pA;
                floatx2 a0 = __builtin_amdgcn_cvt_pk_f32_fp8(uA, false);
                floatx2 a1 = __builtin_amdgcn_cvt_pk_f32_fp8(uA, true);
                acc.x += pA * a0.x; acc.y += pA * a0.y;
                acc.z += pA * a1.x; acc.w += pA * a1.y;
            }
        }
        int nov = *ovf_cnt;
        for (int i = 0; i < nov; i++) {
            int s2 = ovf[2 * i], d2 = ovf[2 * i + 1];
            if (d2 != d) continue;
            float4 as4 = *(const float4*)&a_s[s2 * 4];
            float lg[4];
            float e0 = as4.x + ad4.x; lg[0] = e0 > 0.f ? e0 : SLOPE * e0;
            float e1 = as4.y + ad4.y; lg[1] = e1 > 0.f ? e1 : SLOPE * e1;
            float e2 = as4.z + ad4.z; lg[2] = e2 > 0.f ? e2 : SLOPE * e2;
            float e3 = as4.w + ad4.w; lg[3] = e3 > 0.f ? e3 : SLOPE * e3;
            float mmax = fmaxf(fmaxf(lg[0], lg[1]), fmaxf(lg[2], lg[3]));
            float m_new = fmaxf(m_old, mmax);
            float alpha = __expf(m_old - m_new);
            m_old = m_new;
            float ph = __expf(lg[hd] - m_new);
            acc.x *= alpha; acc.y *= alpha; acc.z *= alpha; acc.w *= alpha;
            den = den * alpha + ph;
            int u = (int)H1[s2 * 64 + lane];
            floatx2 a0 = __builtin_amdgcn_cvt_pk_f32_fp8(u, false);
            floatx2 a1 = __builtin_amdgcn_cvt_pk_f32_fp8(u, true);
            acc.x += ph * a0.x; acc.y += ph * a0.y;
            acc.z += ph * a1.x; acc.w += ph * a1.y;
        }
    }
    float inv = 1.f / den;
    int c0 = lane * 4;
    float4 bi = *(const float4*)&bias[c0];
    float4 gg = *(const float4*)&g[c0];
    float4 bb = *(const float4*)&be[c0];
    float4 mm4 = *(const float4*)&rm[c0];
    float4 vv = *(const float4*)&rv[c0];
    float v0 = fmaxf(acc.x * inv + bi.x, 0.f);
    float v1 = fmaxf(acc.y * inv + bi.y, 0.f);
    float v2 = fmaxf(acc.z * inv + bi.z, 0.f);
    float v3 = fmaxf(acc.w * inv + bi.w, 0.f);
    v0 = (v0 - mm4.x) * rsqrtf(vv.x + BN_EPS) * gg.x + bb.x;
    v1 = (v1 - mm4.y) * rsqrtf(vv.y + BN_EPS) * gg.y + bb.y;
    v2 = (v2 - mm4.z) * rsqrtf(vv.z + BN_EPS) * gg.z + bb.z;
    v3 = (v3 - mm4.w) * rsqrtf(vv.w + BN_EPS) * gg.w + bb.w;
    if (!POOL) {
        unsigned long long o =
            (unsigned long long)f2bf(v0) |
            ((unsigned long long)f2bf(v1) << 16) |
            ((unsigned long long)f2bf(v2) << 32) |
            ((unsigned long long)f2bf(v3) << 48);
        __builtin_nontemporal_store(o, (unsigned long long*)&out16[(long long)d * FEAT + c0]);
    } else {
        shv[w][lane] = make_float4(v0, v1, v2, v3);
        if (lane == 0) shg[w] = (int)batch[d];
        __syncthreads();
        int cl = t >> 2, ce = t & 3;
        float r0 = ((const float*)&shv[0][cl])[ce];
        float r1 = ((const float*)&shv[1][cl])[ce];
        float r2 = ((const float*)&shv[2][cl])[ce];
        float r3 = ((const float*)&shv[3][cl])[ce];
        int g0 = shg[0], g1 = shg[1], g2 = shg[2], g3 = shg[3];
        if (g0 == g3) {           // sorted batch: g0==g3 -> all equal
            atomicAdd(&pooled[g0 * FEAT + t], r0 + r1 + r2 + r3);
        } else {
            float sum = r0;
            int gp = g0;
            if (g1 == gp) sum += r1; else { atomicAdd(&pooled[gp * FEAT + t], sum); gp = g1; sum = r1; }
            if (g2 == gp) sum += r2; else { atomicAdd(&pooled[gp * FEAT + t], sum); gp = g2; sum = r2; }
            if (g3 == gp) sum += r3; else { atomicAdd(&pooled[gp * FEAT + t], sum); gp = g3; sum = r3; }
            atomicAdd(&pooled[gp * FEAT + t], sum);
        }
    }
}

__global__ __launch_bounds__(256) void gat1(
    const int* __restrict__ deg_arr, const int* __restrict__ ell,
    const int* __restrict__ ovf_cnt, const int* __restrict__ ovf,
    const float* __restrict__ a_s, const float* __restrict__ a_d,
    const unsigned char* __restrict__ h8, const float* __restrict__ bias,
    const float* __restrict__ g, const float* __restrict__ be,
    const float* __restrict__ rm, const float* __restrict__ rv,
    unsigned short* __restrict__ out16) {
    gat_core<false>(deg_arr, ell, ovf_cnt, ovf, a_s, a_d, h8, bias, g, be,
                    rm, rv, out16, nullptr, nullptr);
}

__global__ __launch_bounds__(256) void gat2_pool(
    const int* __restrict__ deg_arr, const int* __restrict__ ell,
    const int* __restrict__ ovf_cnt, const int* __restrict__ ovf,
    const float* __restrict__ a_s, const float* __restrict__ a_d,
    const unsigned char* __restrict__ h8, const float* __restrict__ bias,
    const float* __restrict__ g, const float* __restrict__ be,
    const float* __restrict__ rm, const float* __restrict__ rv,
    const int* __restrict__ batch, float* __restrict__ pooled) {
    gat_core<true>(deg_arr, ell, ovf_cnt, ovf, a_s, a_d, h8, bias, g, be,
                   rm, rv, nullptr, batch, pooled);
}

// ===== head: pooled/cnt -> relu(@lw1+lb1) @ lw2 + lb2 =====
__global__ __launch_bounds__(256) void head_mlp(
    const float* __restrict__ pooled, const int* __restrict__ batch,
    const float* __restrict__ lw1, const float* __restrict__ lb1,
    const float* __restrict__ lw2, const float* __restrict__ lb2,
    float* __restrict__ out) {
    int gph = blockIdx.x;
    int t = threadIdx.x;
    __shared__ float pl[FEAT];
    __shared__ float zl[OUT_DIM];
    __shared__ int lo_s, hi_s;
    if (t == 0) {
        int lo = 0, hi = N_NODES;
        while (lo < hi) { int mid = (lo + hi) >> 1; if (batch[mid] < gph) lo = mid + 1; else hi = mid; }
        lo_s = lo;
        int lo2 = 0, hi2 = N_NODES;
        while (lo2 < hi2) { int mid = (lo2 + hi2) >> 1; if (batch[mid] < gph + 1) lo2 = mid + 1; else hi2 = mid; }
        hi_s = lo2;
    }
    __syncthreads();
    float cnt = fmaxf((float)(hi_s - lo_s), 1.f);
    pl[t] = pooled[gph * FEAT + t] / cnt;
    __syncthreads();
    int j = t >> 1, kh = t & 1;
    float zp = 0.f;
    #pragma unroll 8
    for (int k = kh * 128; k < kh * 128 + 128; k++)
        zp += pl[k] * lw1[k * OUT_DIM + j];
    zp += __shfl_xor(zp, 1);
    if (kh == 0) zl[j] = fmaxf(zp + lb1[j], 0.f);
    __syncthreads();
    int w = t >> 6, lane = t & 63;
    if (w < 2) {
        float p = zl[lane] * lw2[lane * 2 + w] + zl[lane + 64] * lw2[(lane + 64) * 2 + w];
        #pragma unroll
        for (int off = 1; off < 64; off <<= 1) p += __shfl_xor(p, off);
        if (lane == 0) out[gph * 2 + w] = p + lb2[w];
    }
}

extern "C" void kernel_launch(void* const* d_in, const int* in_sizes, int n_in,
                              void* d_out, int out_size, void* d_ws, size_t ws_size,
                              hipStream_t stream) {
    const float* x       = (const float*)d_in[0];
    const int*   ei      = (const int*)d_in[1];
    const int*   batch   = (const int*)d_in[2];
    const float* W1      = (const float*)d_in[3];
    const float* att_s1  = (const float*)d_in[4];
    const float* att_d1  = (const float*)d_in[5];
    const float* b1      = (const float*)d_in[6];
    const float* g1      = (const float*)d_in[7];
    const float* be1     = (const float*)d_in[8];
    const float* rm1     = (const float*)d_in[9];
    const float* rv1     = (const float*)d_in[10];
    const float* W2      = (const float*)d_in[11];
    const float* att_s2  = (const float*)d_in[12];
    const float* att_d2  = (const float*)d_in[13];
    const float* b2      = (const float*)d_in[14];
    const float* g2      = (const float*)d_in[15];
    const float* be2     = (const float*)d_in[16];
    const float* rm2     = (const float*)d_in[17];
    const float* rv2     = (const float*)d_in[18];
    const float* lw1     = (const float*)d_in[19];
    const float* lb1     = (const float*)d_in[20];
    const float* lw2     = (const float*)d_in[21];
    const float* lb2     = (const float*)d_in[22];
    float* out           = (float*)d_out;

    const int* src = ei;
    const int* dst = ei + N_EDGES;

    char* p = (char*)d_ws;
    auto carve = [&p](size_t bytes) -> void* {
        void* r = (void*)p;
        p += (bytes + 63) & ~(size_t)63;
        return r;
    };
    float* pooled = (float*)carve(sizeof(float) * NG * FEAT);
    float* a_s    = (float*)carve(sizeof(float) * N_NODES * HEADS);
    float* a_d    = (float*)carve(sizeof(float) * N_NODES * HEADS);
    int*   deg    = (int*)carve(sizeof(int) * N_NODES);
    int*   ovf_cnt= (int*)carve(sizeof(int) * 16);
    int*   ell    = (int*)carve(sizeof(int) * (size_t)N_NODES * ECAP);
    int*   ovf    = (int*)carve(sizeof(int) * 2 * (N_EDGES + N_NODES));
    unsigned char*  h8   = (unsigned char*)carve((size_t)M_PAD * FEAT);
    unsigned short* h1bf = (unsigned short*)carve(sizeof(short) * (size_t)M_PAD * FEAT);
    unsigned short* w1t  = (unsigned short*)carve(sizeof(short) * FEAT * F_IN);
    unsigned short* w2t  = (unsigned short*)carve(sizeof(short) * FEAT * FEAT);

    // ---- prep: W1T, h1bf pad, deg/ell self-init, pooled zero ----
    prep_small<<<NBLK_PREP, 256, 0, stream>>>(W1, w1t, h1bf, deg, ell, ovf_cnt,
                                              (float4*)pooled);

    // ---- Layer 1: GEMM | W2T | ELL build (build last), one launch ----
    gemm1_build<<<NBLK_GEMM + NBLK_W2T + NBLK_BUILD, 256, 0, stream>>>(
        x, w1t, W2, w2t, att_s1, att_d1, h8, a_s, a_d,
        src, dst, deg, ell, ovf_cnt, ovf);
    gat1<<<NBLK_GAT, 256, 0, stream>>>(deg, ell, ovf_cnt, ovf, a_s, a_d, h8,
                                       b1, g1, be1, rm1, rv1, h1bf);

    // ---- Layer 2: 128-row tiles; gat2 fuses BN+pool ----
    gemm2k<<<NBLK_GEMM2, 256, 0, stream>>>(
        h1bf, w2t, att_s2, att_d2, h8, a_s, a_d);
    gat2_pool<<<NBLK_GAT, 256, 0, stream>>>(deg, ell, ovf_cnt, ovf, a_s, a_d,
                                            h8, b2, g2, be2, rm2, rv2,
                                            batch, pooled);

    // ---- head MLP ----
    head_mlp<<<NG, 256, 0, stream>>>(pooled, batch, lw1, lb1, lw2, lb2, out);
}